// Round 4
// baseline (1381.122 us; speedup 1.0000x reference)
//
#include <hip/hip_runtime.h>
#include <hip/hip_bf16.h>
#include <stdint.h>

// h_t = Lam @ h_{t-1} + B @ x_t ; BS=16, T=4096, D=256, fp32 in/out.
// Three-level chunked scan: c1=16 (C1=256/batch), super=8 chunks, supersuper=8,
// sequential combine over 4. 7 dispatches total:
//   memset(bar) / prep (powers+packs, grid-barriered) / Bx GEMM / k5_scan(16 steps)
//   / S GEMM / tail (S2+S3+combine+expand3+expand2, grid-barriered) / carry GEMM.

typedef short v8s __attribute__((ext_vector_type(8)));   // 8 x bf16
typedef float v4f __attribute__((ext_vector_type(4)));   // MFMA accum
typedef unsigned short u16;

static __device__ __forceinline__ u16 f2u(float f) {
  union { float f; unsigned int u; } x; x.f = f;
  unsigned int u = x.u + 0x7FFFu + ((x.u >> 16) & 1u);   // RNE f32->bf16
  return (u16)(u >> 16);
}
static __device__ __forceinline__ float u2f(u16 h) {
  union { unsigned int u; float f; } x; x.u = ((unsigned int)h) << 16;
  return x.f;
}
static __device__ __forceinline__ void lds_barrier() {
  asm volatile("s_waitcnt lgkmcnt(0)\n\ts_barrier" ::: "memory");
}
// Software grid barrier (all blocks co-resident: grid<=256, modest resources).
static __device__ __forceinline__ void grid_bar(unsigned* bar, unsigned nblk) {
  __syncthreads();
  if (threadIdx.x == 0) {
    unsigned g = __hip_atomic_load(bar + 1, __ATOMIC_RELAXED, __HIP_MEMORY_SCOPE_AGENT);
    unsigned arr = __hip_atomic_fetch_add(bar, 1u, __ATOMIC_ACQ_REL, __HIP_MEMORY_SCOPE_AGENT);
    if (arr + 1u == nblk) {
      __hip_atomic_store(bar, 0u, __ATOMIC_RELAXED, __HIP_MEMORY_SCOPE_AGENT);
      __hip_atomic_store(bar + 1, g + 1u, __ATOMIC_RELEASE, __HIP_MEMORY_SCOPE_AGENT);
    } else {
      while (__hip_atomic_load(bar + 1, __ATOMIC_ACQUIRE, __HIP_MEMORY_SCOPE_AGENT) == g)
        __builtin_amdgcn_s_sleep(4);
    }
  }
  __syncthreads();
}

// Power-table slots: 0..16 = Lam^0..Lam^16; 17..23 = Lam^{32,48,64,80,96,112,128};
// 24..30 = Lam^{256,384,512,640,768,896,1024}.
static __device__ __forceinline__ int s2slot(int k) { return k == 0 ? 0 : (k == 1 ? 16 : 15 + k); }  // (Lam^16)^k
static __device__ __forceinline__ int s3slot(int k) { return k == 0 ? 0 : 22 + k; }                  // (Lam^128)^k

__device__ const unsigned char PRODS[29][3] = {  // {dst, srcA, srcB} slots
  {2,1,1},
  {3,2,1},{4,2,2},
  {5,4,1},{6,4,2},{7,4,3},{8,4,4},
  {9,8,1},{10,8,2},{11,8,3},{12,8,4},{13,8,5},{14,8,6},{15,8,7},{16,8,8},
  {17,16,16},
  {18,17,16},{19,17,17},
  {20,19,16},{21,19,17},{22,19,18},{23,19,19},
  {24,23,23},
  {25,24,23},{26,24,24},
  {27,26,23},{28,26,24},{29,26,25},{30,26,26},
};
__device__ const unsigned char STG[11] = {0,1,3,7,15,16,18,22,23,25,29};

// ---------------------------------------------------------------------------
// Generic 64x64-tile bf16 MFMA GEMM (standalone dispatches).
// MODE: 0 f32 plain, 1 bf16 plain, 2 bf16 scatter-s (Acat row (r>>3)*2304+256+(r&7)*256),
//       4 f32 += epilogue.
// ---------------------------------------------------------------------------
template<bool A_F32, int MODE>
__global__ __launch_bounds__(256) void gemm_tile(
    const void* __restrict__ Ap, const u16* __restrict__ Bp,
    void* __restrict__ Cp, int lda, int ldb, int ldc, int K)
{
  __shared__ u16 As[64][72];
  __shared__ u16 Bst[64][72];
  const int tid = threadIdx.x;
  const int lane = tid & 63, w = tid >> 6;
  const int q = lane >> 4, ln = lane & 15;
  const long n0 = (long)blockIdx.x * 64;
  const long m0 = (long)blockIdx.y * 64;
  const int sm = tid >> 2;
  const int sk = (tid & 3) << 4;

  v4f acc[4];
#pragma unroll
  for (int i = 0; i < 4; ++i) acc[i] = 0;

  for (int ks = 0; ks < K; ks += 64) {
    __syncthreads();
    if (A_F32) {
      const float* A = (const float*)Ap + (m0 + sm) * (long)lda + ks + sk;
      float4 f[4];
#pragma unroll
      for (int t = 0; t < 4; ++t) f[t] = ((const float4*)A)[t];
      u16* d = &As[sm][sk];
#pragma unroll
      for (int t = 0; t < 4; ++t) {
        d[4*t+0] = f2u(f[t].x); d[4*t+1] = f2u(f[t].y);
        d[4*t+2] = f2u(f[t].z); d[4*t+3] = f2u(f[t].w);
      }
    } else {
      const u16* A = (const u16*)Ap + (m0 + sm) * (long)lda + ks + sk;
      v8s t0 = ((const v8s*)A)[0], t1 = ((const v8s*)A)[1];
      *(v8s*)&As[sm][sk] = t0; *(v8s*)&As[sm][sk + 8] = t1;
    }
    {
      const u16* Bg = Bp + (long)(ks + sm) * ldb + n0 + sk;
      v8s b0 = ((const v8s*)Bg)[0], b1 = ((const v8s*)Bg)[1];
#pragma unroll
      for (int r = 0; r < 8; ++r) Bst[sk + r][sm] = (u16)b0[r];
#pragma unroll
      for (int r = 0; r < 8; ++r) Bst[sk + 8 + r][sm] = (u16)b1[r];
    }
    __syncthreads();
#pragma unroll
    for (int kb = 0; kb < 64; kb += 32) {
      v8s a = *(const v8s*)&As[w*16 + ln][kb + q*8];
#pragma unroll
      for (int nb = 0; nb < 4; ++nb) {
        v8s b = *(const v8s*)&Bst[nb*16 + ln][kb + q*8];
        acc[nb] = __builtin_amdgcn_mfma_f32_16x16x32_bf16(a, b, acc[nb], 0, 0, 0);
      }
    }
  }
#pragma unroll
  for (int nb = 0; nb < 4; ++nb)
#pragma unroll
    for (int r = 0; r < 4; ++r) {
      const long row = m0 + w*16 + q*4 + r;
      const long col = n0 + nb*16 + ln;
      float v = acc[nb][r];
      if (MODE == 0) ((float*)Cp)[row * (long)ldc + col] = v;
      else if (MODE == 1) ((u16*)Cp)[row * (long)ldc + col] = f2u(v);
      else if (MODE == 2) ((u16*)Cp)[(row >> 3) * 2304 + 256 + (row & 7) * 256 + col] = f2u(v);
      else if (MODE == 4) {
        float* Cf = (float*)Cp + row * (long)ldc + col;
        *Cf = *Cf + v;
      }
    }
}

// ---------------------------------------------------------------------------
// prep: init (Bt/LamT/P0/P1) + 10 power-doubling stages (split hi/lo, 3-seg
// MFMA products) + pack stage (all GEMM operands), grid-barriered. 256 blocks.
// ---------------------------------------------------------------------------
__global__ __launch_bounds__(256) void prep(
    const float* __restrict__ Bm, const float* __restrict__ Lam,
    u16* __restrict__ Bt, u16* __restrict__ LamT,
    u16* __restrict__ Phi, u16* __restrict__ Plo,
    u16* __restrict__ Ghat1, u16* __restrict__ Q1,
    u16* __restrict__ G2, u16* __restrict__ G3,
    u16* __restrict__ Qcat2, u16* __restrict__ Qcat3,
    u16* __restrict__ LcThi, u16* __restrict__ LcTlo, unsigned* bar)
{
  __shared__ u16 As[64][72];
  __shared__ u16 Bst[64][72];
  __shared__ u16 tile[64][65];
  const int tid = threadIdx.x;
  const int lane = tid & 63, w = tid >> 6, q = lane >> 4, ln = lane & 15;
  const int sm = tid >> 2, sk = (tid & 3) << 4;

  // init: Bt/LamT (transposed bf16), slot0 = I, slot1 = Lam hi/lo
  {
    const int idx = blockIdx.x * 256 + tid;      // 0..65535
    const int dd = idx >> 8, ee = idx & 255;
    Bt[idx]   = f2u(Bm[ee * 256 + dd]);          // Bt[e][d] = B[d][e] (idx=(e,d): e=dd? careful)
    LamT[idx] = f2u(Lam[ee * 256 + dd]);
    float v = Lam[idx];
    u16 hi = f2u(v);
    Phi[65536 + idx] = hi; Plo[65536 + idx] = f2u(v - u2f(hi));
    Phi[idx] = (dd == ee) ? (u16)0x3F80 : (u16)0;
    Plo[idx] = 0;
  }
  grid_bar(bar, 256);

  // power products
  for (int st = 0; st < 10; ++st) {
    const int s = STG[st], nprod = STG[st + 1] - s;
    const int pi = blockIdx.x >> 4, pt = blockIdx.x & 15;
    if (pi < nprod) {
      const int c = PRODS[s + pi][0], a = PRODS[s + pi][1], b = PRODS[s + pi][2];
      const int m0 = (pt >> 2) * 64, n0 = (pt & 3) * 64;
      v4f acc[4];
#pragma unroll
      for (int i = 0; i < 4; ++i) acc[i] = 0;
      for (int seg = 0; seg < 3; ++seg) {
        const u16* Asrc = ((seg == 1) ? Plo : Phi) + (size_t)a * 65536;
        const u16* Bsrc = ((seg == 2) ? Plo : Phi) + (size_t)b * 65536;
        for (int ks = 0; ks < 256; ks += 64) {
          __syncthreads();
          {
            const u16* Ag = Asrc + (size_t)(m0 + sm) * 256 + ks + sk;
            v8s t0 = ((const v8s*)Ag)[0], t1 = ((const v8s*)Ag)[1];
            *(v8s*)&As[sm][sk] = t0; *(v8s*)&As[sm][sk + 8] = t1;
          }
          {
            const u16* Bg = Bsrc + (size_t)(ks + sm) * 256 + n0 + sk;
            v8s b0 = ((const v8s*)Bg)[0], b1 = ((const v8s*)Bg)[1];
#pragma unroll
            for (int r = 0; r < 8; ++r) Bst[sk + r][sm] = (u16)b0[r];
#pragma unroll
            for (int r = 0; r < 8; ++r) Bst[sk + 8 + r][sm] = (u16)b1[r];
          }
          __syncthreads();
#pragma unroll
          for (int kb = 0; kb < 64; kb += 32) {
            v8s av = *(const v8s*)&As[w*16 + ln][kb + q*8];
#pragma unroll
            for (int nb = 0; nb < 4; ++nb) {
              v8s bv = *(const v8s*)&Bst[nb*16 + ln][kb + q*8];
              acc[nb] = __builtin_amdgcn_mfma_f32_16x16x32_bf16(av, bv, acc[nb], 0, 0, 0);
            }
          }
        }
      }
      const size_t ob = (size_t)c * 65536;
#pragma unroll
      for (int nb = 0; nb < 4; ++nb)
#pragma unroll
        for (int r = 0; r < 4; ++r) {
          const int row = m0 + w*16 + q*4 + r, col = n0 + nb*16 + ln;
          float v = acc[nb][r];
          u16 hi = f2u(v);
          Phi[ob + (size_t)row*256 + col] = hi;
          Plo[ob + (size_t)row*256 + col] = f2u(v - u2f(hi));
        }
    }
    grid_bar(bar, 256);
  }

  // pack stage: dst[doff + B*dld + A] = src[(sr0+A)*256 + sc0+B] (64x64 transpose)
  const int tx = tid & 63, ty = tid >> 6;
  auto tr64 = [&](const u16* src, int sr0, int sc0, u16* dst, size_t doff, int dld) {
    __syncthreads();
#pragma unroll
    for (int s = 0; s < 16; ++s)
      tile[ty*16 + s][tx] = src[(size_t)(sr0 + ty*16 + s) * 256 + sc0 + tx];
    __syncthreads();
#pragma unroll
    for (int s = 0; s < 16; ++s)
      dst[doff + (size_t)(ty*16 + s) * dld + tx] = tile[tx][ty*16 + s];
  };
  auto zero64 = [&](u16* dst, size_t doff, int dld) {
#pragma unroll
    for (int s = 0; s < 16; ++s)
      dst[doff + (size_t)(ty*16 + s) * dld + tx] = 0;
  };
  for (int t = blockIdx.x; t < 3104; t += 256) {
    int tt = t;
    if (tt < 256) {               // Ghat1[(j*256+d)][e] = Lam^{15-j}[e][d]
      const int j = tt >> 4, sub = tt & 15, d0 = (sub & 3) * 64, e0 = (sub >> 2) * 64;
      tr64(Phi + (size_t)(15 - j) * 65536, e0, d0, Ghat1, ((size_t)(j*256 + d0)) * 256 + e0, 256);
    } else if (tt < 512) {        // Q1[e][(j*256+d)] = Lam^{j+1}[d][e]
      tt -= 256;
      const int j = tt >> 4, sub = tt & 15, d0 = (sub & 3) * 64, e0 = (sub >> 2) * 64;
      tr64(Phi + (size_t)(j + 1) * 65536, d0, e0, Q1, (size_t)e0 * 4096 + j*256 + d0, 4096);
    } else if (tt < 640) {        // G2[(u*256+d)][e] = (Lam^16)^{7-u}[e][d]
      tt -= 512;
      const int u = tt >> 4, sub = tt & 15, d0 = (sub & 3) * 64, e0 = (sub >> 2) * 64;
      tr64(Phi + (size_t)s2slot(7 - u) * 65536, e0, d0, G2, ((size_t)(u*256 + d0)) * 256 + e0, 256);
    } else if (tt < 768) {        // G3[(u*256+d)][e] = (Lam^128)^{7-u}[e][d]
      tt -= 640;
      const int u = tt >> 4, sub = tt & 15, d0 = (sub & 3) * 64, e0 = (sub >> 2) * 64;
      tr64(Phi + (size_t)s3slot(7 - u) * 65536, e0, d0, G3, ((size_t)(u*256 + d0)) * 256 + e0, 256);
    } else if (tt < 1920) {       // Qcat2 [2304 x 2048]
      tt -= 768;
      const int rt = tt >> 5, ct = tt & 31, u = ct >> 2, d0 = (ct & 3) * 64, k0 = rt * 64;
      const size_t doff = (size_t)k0 * 2048 + u*256 + d0;
      if (k0 < 256) tr64(Phi + (size_t)s2slot(u) * 65536, d0, k0, Qcat2, doff, 2048);
      else {
        const int v = (k0 - 256) >> 8, e0 = (k0 - 256) & 255;
        if (v < u) tr64(Phi + (size_t)s2slot(u - 1 - v) * 65536, d0, e0, Qcat2, doff, 2048);
        else zero64(Qcat2, doff, 2048);
      }
    } else if (tt < 3072) {       // Qcat3 [2304 x 2048]
      tt -= 1920;
      const int rt = tt >> 5, ct = tt & 31, u = ct >> 2, d0 = (ct & 3) * 64, k0 = rt * 64;
      const size_t doff = (size_t)k0 * 2048 + u*256 + d0;
      if (k0 < 256) tr64(Phi + (size_t)s3slot(u) * 65536, d0, k0, Qcat3, doff, 2048);
      else {
        const int v = (k0 - 256) >> 8, e0 = (k0 - 256) & 255;
        if (v < u) tr64(Phi + (size_t)s3slot(u - 1 - v) * 65536, d0, e0, Qcat3, doff, 2048);
        else zero64(Qcat3, doff, 2048);
      }
    } else {                      // LcT[e][d] = Lam^1024[d][e] (hi/lo)
      tt -= 3072;
      const int half = tt >> 4, sub = tt & 15, d0 = (sub & 3) * 64, e0 = (sub >> 2) * 64;
      const u16* src = (half ? Plo : Phi) + (size_t)30 * 65536;
      tr64(src, d0, e0, half ? LcTlo : LcThi, (size_t)e0 * 256 + d0, 256);
    }
  }
}

// ---------------------------------------------------------------------------
// k5_scan: c=16 local scans. 256 blocks x 16 chunk-states, 16 steps.
// Writes g_local (fp32) to Out; carry added later by carry GEMM += epilogue.
// ---------------------------------------------------------------------------
__global__ __launch_bounds__(256, 1) void k5_scan(
    const u16* __restrict__ LamT, const u16* __restrict__ Bx,
    float* __restrict__ Out)
{
  __shared__ u16 gs[16][264];
  const int tid = threadIdx.x, lane = tid & 63, w = tid >> 6;
  const int q = lane >> 4, ln = lane & 15;
  const int b = blockIdx.x >> 4, igrp = blockIdx.x & 15;

  v8s bf[8][4];                       // Lam^T frags, cols [64w, 64w+64)
#pragma unroll
  for (int kk = 0; kk < 8; ++kk)
#pragma unroll
    for (int nb = 0; nb < 4; ++nb) {
      const int n = 64*w + nb*16 + ln;
#pragma unroll
      for (int r = 0; r < 8; ++r)
        bf[kk][nb][r] = (short)LamT[(kk*32 + q*8 + r) * 256 + n];
    }
  for (int e = tid; e < 16*264; e += 256) (&gs[0][0])[e] = 0;

  const size_t base0 = ((size_t)b * 4096 + (size_t)igrp * 256) * 256;
  const int colw = 64*w;

  u16 bxr[2][4][4];                   // depth-2 Bx prefetch ring (all lanes)
#pragma unroll
  for (int s = 0; s < 2; ++s)
#pragma unroll
    for (int r = 0; r < 4; ++r)
#pragma unroll
      for (int nb = 0; nb < 4; ++nb)
        bxr[s][r][nb] = Bx[base0 + (size_t)((4*q + r)*16 + s)*256 + colw + nb*16 + ln];
  lds_barrier();

  for (int j = 0; j < 16; ++j) {
    v8s a[8];
#pragma unroll
    for (int kk = 0; kk < 8; ++kk) a[kk] = *(const v8s*)&gs[ln][kk*32 + q*8];
    lds_barrier();
    v4f acc[4];
#pragma unroll
    for (int nb = 0; nb < 4; ++nb) acc[nb] = 0;
#pragma unroll
    for (int kk = 0; kk < 8; ++kk)
#pragma unroll
      for (int nb = 0; nb < 4; ++nb)
        acc[nb] = __builtin_amdgcn_mfma_f32_16x16x32_bf16(a[kk], bf[kk][nb], acc[nb], 0, 0, 0);
#pragma unroll
    for (int r = 0; r < 4; ++r) {
      const int m = 4*q + r;
      const size_t rb = base0 + (size_t)(m*16 + j)*256 + colw;
#pragma unroll
      for (int nb = 0; nb < 4; ++nb) {
        const float g = acc[nb][r] + u2f(bxr[j & 1][r][nb]);
        Out[rb + nb*16 + ln] = g;
        gs[m][colw + nb*16 + ln] = f2u(g);
      }
    }
    if (j < 14) {
#pragma unroll
      for (int r = 0; r < 4; ++r) {
        const size_t rb = base0 + (size_t)((4*q + r)*16 + j + 2)*256 + colw;
#pragma unroll
        for (int nb = 0; nb < 4; ++nb)
          bxr[j & 1][r][nb] = Bx[rb + nb*16 + ln];
      }
    }
    lds_barrier();
  }
}

// ---------------------------------------------------------------------------
// tail: S2 GEMM -> S3 GEMM -> 4-step combine -> expand3 -> expand2.
// 256 blocks x 512 threads, grid-barriered. GEMM work on waves 0..3.
// ---------------------------------------------------------------------------
static __device__ void gemm_dev(const u16* A, int lda, const u16* B, int ldb,
    void* C, int ldc, int K, int mode, int m0, int n0,
    u16 (*As)[72], u16 (*Bst)[72], int tid)
{
  const bool act = tid < 256;
  const int lane = tid & 63, w = (tid >> 6) & 3;
  const int q = lane >> 4, ln = lane & 15;
  const int sm = tid >> 2, sk = (tid & 3) << 4;
  v4f acc[4];
#pragma unroll
  for (int i = 0; i < 4; ++i) acc[i] = 0;
  for (int ks = 0; ks < K; ks += 64) {
    __syncthreads();
    if (act) {
      {
        const u16* Ag = A + (size_t)(m0 + sm) * lda + ks + sk;
        v8s t0 = ((const v8s*)Ag)[0], t1 = ((const v8s*)Ag)[1];
        *(v8s*)&As[sm][sk] = t0; *(v8s*)&As[sm][sk + 8] = t1;
      }
      {
        const u16* Bg = B + (size_t)(ks + sm) * ldb + n0 + sk;
        v8s b0 = ((const v8s*)Bg)[0], b1 = ((const v8s*)Bg)[1];
#pragma unroll
        for (int r = 0; r < 8; ++r) Bst[sk + r][sm] = (u16)b0[r];
#pragma unroll
        for (int r = 0; r < 8; ++r) Bst[sk + 8 + r][sm] = (u16)b1[r];
      }
    }
    __syncthreads();
    if (act) {
#pragma unroll
      for (int kb = 0; kb < 64; kb += 32) {
        v8s av = *(const v8s*)&As[w*16 + ln][kb + q*8];
#pragma unroll
        for (int nb = 0; nb < 4; ++nb) {
          v8s bv = *(const v8s*)&Bst[nb*16 + ln][kb + q*8];
          acc[nb] = __builtin_amdgcn_mfma_f32_16x16x32_bf16(av, bv, acc[nb], 0, 0, 0);
        }
      }
    }
  }
  if (act) {
#pragma unroll
    for (int nb = 0; nb < 4; ++nb)
#pragma unroll
      for (int r = 0; r < 4; ++r) {
        const long row = m0 + w*16 + q*4 + r;
        const long col = n0 + nb*16 + ln;
        float v = acc[nb][r];
        if (mode == 0) ((float*)C)[row * (long)ldc + col] = v;
        else if (mode == 2) ((u16*)C)[(row >> 3) * 2304 + 256 + (row & 7) * 256 + col] = f2u(v);
        else if (mode == 3) ((u16*)C)[((size_t)(row * 8 + (col >> 8))) * ldc + (col & 255)] = f2u(v);
      }
  }
}

__global__ __launch_bounds__(512, 2) void tail(
    const u16* __restrict__ G2, const u16* __restrict__ G3,
    const u16* __restrict__ Qcat2, const u16* __restrict__ Qcat3,
    const u16* __restrict__ LcThi, const u16* __restrict__ LcTlo,
    u16* __restrict__ Acat2, u16* __restrict__ Acat3,
    float* __restrict__ S3, u16* __restrict__ Abf, unsigned* bar)
{
  __shared__ u16 As[64][72];
  __shared__ u16 Bst[64][72];
  __shared__ u16 Hhi[16][264];
  __shared__ u16 Hlo[16][264];
  const int tid = threadIdx.x;

  // t1: S2[512,256] = Acat2_s[512,2048] @ G2 -> Acat3 s-region
  if (blockIdx.x < 32)
    gemm_dev(Acat2 + 256, 2304, G2, 256, Acat3, 0, 2048, 2,
             (blockIdx.x >> 2) * 64, (blockIdx.x & 3) * 64, As, Bst, tid);
  grid_bar(bar, 256);
  // t2: S3[64,256] = Acat3_s[64,2048] @ G3 (f32)
  if (blockIdx.x < 4)
    gemm_dev(Acat3 + 256, 2304, G3, 256, S3, 256, 2048, 0,
             0, blockIdx.x * 64, As, Bst, tid);
  grid_bar(bar, 256);
  // t3: sequential combine over 4 supersuperchunks (block 0, 8 waves)
  if (blockIdx.x == 0) {
    const int lane = tid & 63, w = tid >> 6, q = lane >> 4, ln = lane & 15;
    v8s bhi[8][2], blo[8][2];
#pragma unroll
    for (int kk = 0; kk < 8; ++kk)
#pragma unroll
      for (int nb = 0; nb < 2; ++nb) {
        const int n = 32*w + nb*16 + ln;
#pragma unroll
        for (int r = 0; r < 8; ++r) {
          const int k = kk*32 + q*8 + r;
          bhi[kk][nb][r] = (short)LcThi[k*256 + n];
          blo[kk][nb][r] = (short)LcTlo[k*256 + n];
        }
      }
    for (int e = tid; e < 16*264; e += 512) { (&Hhi[0][0])[e] = 0; (&Hlo[0][0])[e] = 0; }
    lds_barrier();
    for (int m = 0; m < 4; ++m) {
      for (int e = tid; e < 4096; e += 512) {
        const int bb = e >> 8, d = e & 255;
        Acat3[(size_t)(bb*4 + m) * 2304 + d] = Hhi[bb][d];
      }
      v8s ahi[8], alo[8];
#pragma unroll
      for (int kk = 0; kk < 8; ++kk) {
        ahi[kk] = *(const v8s*)&Hhi[ln][kk*32 + q*8];
        alo[kk] = *(const v8s*)&Hlo[ln][kk*32 + q*8];
      }
      lds_barrier();
      v4f acc[2];
#pragma unroll
      for (int nb = 0; nb < 2; ++nb)
#pragma unroll
        for (int r = 0; r < 4; ++r)
          acc[nb][r] = S3[(size_t)((4*q + r)*4 + m)*256 + 32*w + nb*16 + ln];
#pragma unroll
      for (int kk = 0; kk < 8; ++kk)
#pragma unroll
        for (int nb = 0; nb < 2; ++nb) {
          acc[nb] = __builtin_amdgcn_mfma_f32_16x16x32_bf16(ahi[kk], bhi[kk][nb], acc[nb], 0, 0, 0);
          acc[nb] = __builtin_amdgcn_mfma_f32_16x16x32_bf16(alo[kk], bhi[kk][nb], acc[nb], 0, 0, 0);
          acc[nb] = __builtin_amdgcn_mfma_f32_16x16x32_bf16(ahi[kk], blo[kk][nb], acc[nb], 0, 0, 0);
        }
#pragma unroll
      for (int nb = 0; nb < 2; ++nb)
#pragma unroll
        for (int r = 0; r < 4; ++r) {
          const int bb = 4*q + r, col = 32*w + nb*16 + ln;
          float v = acc[nb][r];
          u16 hi = f2u(v);
          Hhi[bb][col] = hi;
          Hlo[bb][col] = f2u(v - u2f(hi));
        }
      lds_barrier();
    }
  }
  grid_bar(bar, 256);
  // t4: expand3: A2 = Acat3[64,2304] @ Qcat3 -> Acat2 A-region
  if (blockIdx.x < 32)
    gemm_dev(Acat3, 2304, Qcat3, 2048, Acat2, 2304, 2304, 3,
             0, blockIdx.x * 64, As, Bst, tid);
  grid_bar(bar, 256);
  // t5: expand2: A1 = Acat2[512,2304] @ Qcat2 -> Abf[4096,256]
  gemm_dev(Acat2, 2304, Qcat2, 2048, Abf, 256, 2304, 3,
           (blockIdx.x >> 5) * 64, (blockIdx.x & 31) * 64, As, Bst, tid);
}

// ---------------------------------------------------------------------------
extern "C" void kernel_launch(void* const* d_in, const int* in_sizes, int n_in,
                              void* d_out, int out_size, void* d_ws, size_t ws_size,
                              hipStream_t stream)
{
  const float* x   = (const float*)d_in[0];
  const float* Bm  = (const float*)d_in[1];
  const float* Lam = (const float*)d_in[2];
  float* Out = (float*)d_out;
  (void)in_sizes; (void)n_in; (void)out_size; (void)ws_size;

  char* ws = (char*)d_ws;
  size_t off = 0;
  auto alloc = [&](size_t bytes) { void* p = ws + off; off += (bytes + 255) & ~(size_t)255; return p; };
  u16* Bx     = (u16*)alloc((size_t)16777216 * 2);       // [65536,256] bf16
  u16* Phi    = (u16*)alloc((size_t)31 * 65536 * 2);     // power table hi
  u16* Plo    = (u16*)alloc((size_t)31 * 65536 * 2);     // power table lo
  u16* Ghat1  = (u16*)alloc((size_t)4096 * 256 * 2);
  u16* Q1     = (u16*)alloc((size_t)256 * 4096 * 2);
  u16* G2     = (u16*)alloc((size_t)2048 * 256 * 2);
  u16* G3     = (u16*)alloc((size_t)2048 * 256 * 2);
  u16* Qcat2  = (u16*)alloc((size_t)2304 * 2048 * 2);
  u16* Qcat3  = (u16*)alloc((size_t)2304 * 2048 * 2);
  u16* Bt     = (u16*)alloc(131072);
  u16* LamT   = (u16*)alloc(131072);
  u16* LcThi  = (u16*)alloc(131072);
  u16* LcTlo  = (u16*)alloc(131072);
  u16* Acat2  = (u16*)alloc((size_t)512 * 2304 * 2);     // [A2 | s x8] per (b,m2)
  u16* Acat3  = (u16*)alloc((size_t)64 * 2304 * 2);      // [A3 | s2 x8] per (b,m3)
  float* S3   = (float*)alloc((size_t)64 * 256 * 4);
  u16* Abf    = (u16*)alloc((size_t)4096 * 256 * 2);
  unsigned* bar = (unsigned*)alloc(256);

  hipMemsetAsync(bar, 0, 128, stream);
  // powers + operand packs (grid-barriered, 1 dispatch)
  prep<<<dim3(256), dim3(256), 0, stream>>>(Bm, Lam, Bt, LamT, Phi, Plo,
      Ghat1, Q1, G2, G3, Qcat2, Qcat3, LcThi, LcTlo, bar);
  // Bx = x @ B^T (bf16)
  gemm_tile<true, 1><<<dim3(4, 1024), dim3(256), 0, stream>>>(
      (const void*)x, Bt, (void*)Bx, 256, 256, 256, 256);
  // local scans (16 steps)
  k5_scan<<<dim3(256), dim3(256), 0, stream>>>(LamT, Bx, Out);
  // chunk summaries: S[4096,256] = Bx_r[4096,4096] @ Ghat1 -> Acat2 s-region
  gemm_tile<false, 2><<<dim3(4, 64), dim3(256), 0, stream>>>(
      (const void*)Bx, Ghat1, (void*)Acat2, 4096, 256, 2304, 4096);
  // S2 / S3 / combine / expand3 / expand2 (grid-barriered, 1 dispatch)
  tail<<<dim3(256), dim3(512), 0, stream>>>(G2, G3, Qcat2, Qcat3,
      LcThi, LcTlo, Acat2, Acat3, S3, Abf, bar + 16);
  // carry GEMM: Out[(b,i)][(j,d)] += Abf @ Q1  (layout == [b,t,d])
  gemm_tile<false, 4><<<dim3(64, 64), dim3(256), 0, stream>>>(
      (const void*)Abf, Q1, (void*)Out, 256, 4096, 4096, 256);
}